// Round 16
// baseline (78.461 us; speedup 1.0000x reference)
//
#include <hip/hip_runtime.h>

// SpectralConv2d via pruned partial DFTs (h-DFT first), 3-kernel fused pipeline.
// x: [16,32,256,256] f32 ; w1,w2: [32,32,12,12,2] f32 ; out: [16,32,256,256] f32
//  K12: per-bi block (grid 512): radix-4 h-fold H-DFT. Lane = 4 w (float4) so a wave
//       reads FULL 1KB rows; waves interleave h' (q = h' mod 4) so each block drives
//       exactly 4 contiguous streams (r16 theory: all prior variants' 512B/1KB-stride
//       fragmented streams pinned reads at ~3TB/s regardless of in-flight depth).
//       LDS reduce -> fused full-width w-DFT -> Xf (single copy, no half fixup).
//  K3:  F[ky][kx][bo] = channel mix; scale (kx==0?1:2)/65536 folded in.
//  K45: per bo block: inverse ky-DFT -> G[bo] in LDS, then inverse w-DFT -> out.

#define TPI 6.28318530717958647692f

__global__ __launch_bounds__(256, 2) void k12_hwdft(const float* __restrict__ x,
                                                    float* __restrict__ Xf) {
  __shared__ float2 step2[64];        // (cos,sin)(2pi h'/256), h'=0..63 (0.5 KB)
  __shared__ float red[4 * 7 * 256];  // cross-wave reduce (28 KB)
  __shared__ float2 Ys2[13 * 257];    // [j][w] {C,S}, stride 257 (26.7 KB)
  const int bi = blockIdx.x;          // 0..511
  const int t = threadIdx.x;
  const int q = t >> 6, l = t & 63;   // wave q -> h' = 4i+q, lane l -> w = 4l..4l+3

  if (t < 64) {
    float s, c;
    sincosf(TPI * (float)t * (1.0f / 256.0f), &s, &c);
    step2[t] = make_float2(c, s);
  }
  __syncthreads();

  const float4* xp4 = reinterpret_cast<const float4*>(x + (size_t)bi * 65536) + l;
  float4 aC[13], aS12[12];            // aS12[j-1] holds S_j (S_0 == 0)
#pragma unroll
  for (int j = 0; j < 13; j++) aC[j] = make_float4(0.f, 0.f, 0.f, 0.f);
#pragma unroll
  for (int j = 0; j < 12; j++) aS12[j] = make_float4(0.f, 0.f, 0.f, 0.f);

#pragma unroll 2
  for (int i = 0; i < 16; i++) {
    const int h = 4 * i + q;          // h' in [0,64), waves interleaved
    float4 x0 = xp4[h * 64];          // 4 contiguous streams per block
    float4 x1 = xp4[(h + 64) * 64];
    float4 x2 = xp4[(h + 128) * 64];
    float4 x3 = xp4[(h + 192) * 64];
    // radix-4 folds (algebra verified r15)
    float4 p02 = make_float4(x0.x + x2.x, x0.y + x2.y, x0.z + x2.z, x0.w + x2.w);
    float4 m02 = make_float4(x0.x - x2.x, x0.y - x2.y, x0.z - x2.z, x0.w - x2.w);
    float4 p13 = make_float4(x1.x + x3.x, x1.y + x3.y, x1.z + x3.z, x1.w + x3.w);
    float4 m13 = make_float4(x1.x - x3.x, x1.y - x3.y, x1.z - x3.z, x1.w - x3.w);
    float4 A = make_float4(p02.x + p13.x, p02.y + p13.y, p02.z + p13.z, p02.w + p13.w);
    float4 Bv = make_float4(p02.x - p13.x, p02.y - p13.y, p02.z - p13.z, p02.w - p13.w);
    aC[0].x += A.x; aC[0].y += A.y; aC[0].z += A.z; aC[0].w += A.w;  // j=0
    float2 st = step2[h];
    float cj = st.x, sj = st.y;       // phasor (cos j*th', sin j*th') at j=1
#pragma unroll
    for (int jj = 0; jj < 12; jj++) {
      const int j = jj + 1, r = j & 3;
      if (r == 0) {
        aC[j].x = fmaf(A.x, cj, aC[j].x); aC[j].y = fmaf(A.y, cj, aC[j].y);
        aC[j].z = fmaf(A.z, cj, aC[j].z); aC[j].w = fmaf(A.w, cj, aC[j].w);
        aS12[jj].x = fmaf(A.x, sj, aS12[jj].x); aS12[jj].y = fmaf(A.y, sj, aS12[jj].y);
        aS12[jj].z = fmaf(A.z, sj, aS12[jj].z); aS12[jj].w = fmaf(A.w, sj, aS12[jj].w);
      } else if (r == 2) {
        aC[j].x = fmaf(Bv.x, cj, aC[j].x); aC[j].y = fmaf(Bv.y, cj, aC[j].y);
        aC[j].z = fmaf(Bv.z, cj, aC[j].z); aC[j].w = fmaf(Bv.w, cj, aC[j].w);
        aS12[jj].x = fmaf(Bv.x, sj, aS12[jj].x); aS12[jj].y = fmaf(Bv.y, sj, aS12[jj].y);
        aS12[jj].z = fmaf(Bv.z, sj, aS12[jj].z); aS12[jj].w = fmaf(Bv.w, sj, aS12[jj].w);
      } else if (r == 1) {
        // C += m02*c - m13*s ; S += m02*s + m13*c
        aC[j].x = fmaf(m02.x, cj, fmaf(-m13.x, sj, aC[j].x));
        aC[j].y = fmaf(m02.y, cj, fmaf(-m13.y, sj, aC[j].y));
        aC[j].z = fmaf(m02.z, cj, fmaf(-m13.z, sj, aC[j].z));
        aC[j].w = fmaf(m02.w, cj, fmaf(-m13.w, sj, aC[j].w));
        aS12[jj].x = fmaf(m02.x, sj, fmaf(m13.x, cj, aS12[jj].x));
        aS12[jj].y = fmaf(m02.y, sj, fmaf(m13.y, cj, aS12[jj].y));
        aS12[jj].z = fmaf(m02.z, sj, fmaf(m13.z, cj, aS12[jj].z));
        aS12[jj].w = fmaf(m02.w, sj, fmaf(m13.w, cj, aS12[jj].w));
      } else {  // r == 3
        aC[j].x = fmaf(m02.x, cj, fmaf(m13.x, sj, aC[j].x));
        aC[j].y = fmaf(m02.y, cj, fmaf(m13.y, sj, aC[j].y));
        aC[j].z = fmaf(m02.z, cj, fmaf(m13.z, sj, aC[j].z));
        aC[j].w = fmaf(m02.w, cj, fmaf(m13.w, sj, aC[j].w));
        aS12[jj].x = fmaf(m02.x, sj, fmaf(-m13.x, cj, aS12[jj].x));
        aS12[jj].y = fmaf(m02.y, sj, fmaf(-m13.y, cj, aS12[jj].y));
        aS12[jj].z = fmaf(m02.z, sj, fmaf(-m13.z, cj, aS12[jj].z));
        aS12[jj].w = fmaf(m02.w, sj, fmaf(-m13.w, cj, aS12[jj].w));
      }
      if (jj < 11) {
        float nc = fmaf(cj, st.x, -(sj * st.y));  // rotate by e^{i th'}
        float ns = fmaf(cj, st.y, sj * st.x);
        cj = nc; sj = ns;
      }
    }
  }

  // cross-wave reduce into LDS Ys2: 4 passes x 7 classes (cls = 2j: C_j, 2j+1: S_j)
  for (int p = 0; p < 4; p++) {
    __syncthreads();
#pragma unroll
    for (int cc = 0; cc < 7; cc++) {
      int cls = p * 7 + cc;
      if (cls < 26) {
        int j = cls >> 1;
        float4 v;
        if (cls & 1) v = (j == 0) ? make_float4(0.f, 0.f, 0.f, 0.f) : aS12[j - 1];
        else v = aC[j];
        *reinterpret_cast<float4*>(&red[(q * 7 + cc) * 256 + 4 * l]) = v;
      }
    }
    __syncthreads();
    for (int idx = t; idx < 7 * 256; idx += 256) {
      int cc = idx >> 8, wl = idx & 255;
      int cls = p * 7 + cc;
      if (cls < 26) {
        float s = red[(0 * 7 + cc) * 256 + wl] + red[(1 * 7 + cc) * 256 + wl] +
                  red[(2 * 7 + cc) * 256 + wl] + red[(3 * 7 + cc) * 256 + wl];
        if (cls & 1) Ys2[(cls >> 1) * 257 + wl].y = s;
        else         Ys2[(cls >> 1) * 257 + wl].x = s;
      }
    }
  }
  __syncthreads();

  // fused w-DFT: full 256-w sum, direct Xf write (no half fixup)
  if (t < 156) {
    int j = t / 12, kx = t % 12;  // j = |ky| 0..12
    float cs, ss;
    {
      float s, c;
      sincosf(TPI * (float)kx * (1.0f / 256.0f), &s, &c);
      cs = c; ss = -s;  // step phasor e^{-i kx theta}
    }
    const float2* CS = &Ys2[j * 257];
    float pr = 1.0f, pi = 0.0f;
    float A = 0, B = 0, D = 0, E = 0;
#pragma unroll 4
    for (int w = 0; w < 256; w++) {
      float2 v = CS[w];
      A = fmaf(v.x, pr, A);
      B = fmaf(v.x, pi, B);
      D = fmaf(v.y, pr, D);
      E = fmaf(v.y, pi, E);
      float npr = pr * cs - pi * ss;
      float npi = pr * ss + pi * cs;
      pr = npr; pi = npi;
    }
    // X[ky=j]: re = A + E, im = B - D ; X[24-j]: re = A - E, im = B + D
    float2* Xo = reinterpret_cast<float2*>(Xf);
    size_t base = (size_t)kx * 512 + bi;
    if (j <= 11) Xo[(size_t)j * 6144 + base] = make_float2(A + E, B - D);
    if (j >= 1)  Xo[(size_t)(24 - j) * 6144 + base] = make_float2(A - E, B + D);
  }
}

__global__ __launch_bounds__(256) void k3_mix(const float* __restrict__ Xf,
                                              const float* __restrict__ w1,
                                              const float* __restrict__ w2,
                                              float* __restrict__ Ff) {
  __shared__ float Xs[1024];  // [b][i][2]
  __shared__ float Ws[2048];  // [i][o][2]
  int m = blockIdx.x;         // ky*12 + kx, 288 blocks
  int ky = m / 12, kx = m % 12;
  int t = threadIdx.x;
  const float* Xsl = Xf + (size_t)m * 1024;
  for (int e = t; e < 1024; e += 256) Xs[e] = Xsl[e];
  const float* Wp = (ky < 12) ? w1 : w2;
  int myr = (ky < 12) ? ky : ky - 12;
  int woff = myr * 24 + kx * 2;
  for (int e = t; e < 1024; e += 256) {  // e = i*32 + o
    float2 wv = *reinterpret_cast<const float2*>(Wp + (size_t)e * 288 + woff);
    Ws[e * 2] = wv.x; Ws[e * 2 + 1] = wv.y;
  }
  __syncthreads();
  int o = t & 31, bh = t >> 5;  // bh 0..7 ; handles b = bh and bh+8
  float ar = 0, ai = 0, br = 0, bi_ = 0;
#pragma unroll
  for (int i = 0; i < 32; i++) {
    float wr = Ws[i * 64 + o * 2], wi = Ws[i * 64 + o * 2 + 1];
    float x1r = Xs[bh * 64 + i * 2], x1i = Xs[bh * 64 + i * 2 + 1];
    float x2r = Xs[(bh + 8) * 64 + i * 2], x2i = Xs[(bh + 8) * 64 + i * 2 + 1];
    ar = fmaf(x1r, wr, ar); ar = fmaf(-x1i, wi, ar);
    ai = fmaf(x1r, wi, ai); ai = fmaf(x1i, wr, ai);
    br = fmaf(x2r, wr, br); br = fmaf(-x2i, wi, br);
    bi_ = fmaf(x2r, wi, bi_); bi_ = fmaf(x2i, wr, bi_);
  }
  float scale = (kx == 0 ? 1.0f : 2.0f) * (1.0f / 65536.0f);
  float2* Fo = reinterpret_cast<float2*>(Ff) + (size_t)m * 512;
  Fo[(size_t)bh * 32 + o] = make_float2(ar * scale, ai * scale);
  Fo[(size_t)(bh + 8) * 32 + o] = make_float2(br * scale, bi_ * scale);
}

__global__ __launch_bounds__(256) void k45_inv(const float* __restrict__ Ff,
                                               float* __restrict__ out) {
  __shared__ float tw[128 * 27];     // [h][2j+{c,s}], pad 27 (13.8 KB)
  __shared__ float PQ[13 * 12 * 4];  // [j][kx][{Pr,Pi,Qr,Qi}] (2.4 KB)
  __shared__ float Gs[256 * 24];     // G[bo] rows (24.6 KB)
  const int bo = blockIdx.x;         // 0..511
  const int t = threadIdx.x;         // 0..255
  const int l = t & 63, wq = t >> 6;

  for (int e = t; e < 128 * 13; e += 256) {
    int h = e / 13, j = e % 13;
    float s, c;
    sincosf(TPI * (float)((h * j) & 255) * (1.0f / 256.0f), &s, &c);
    tw[h * 27 + 2 * j] = c;
    tw[h * 27 + 2 * j + 1] = s;
  }
  if (t < 156) {
    int j = t / 12, kx = t % 12;
    const float2* F2 = reinterpret_cast<const float2*>(Ff);
    float lr = 0, li = 0, hr = 0, hi = 0;
    if (j < 12) { float2 v = F2[((size_t)j * 12 + kx) * 512 + bo]; lr = v.x; li = v.y; }
    if (j > 0)  { float2 v = F2[((size_t)(24 - j) * 12 + kx) * 512 + bo]; hr = v.x; hi = v.y; }
    PQ[(j * 12 + kx) * 4 + 0] = lr + hr;  // Pr
    PQ[(j * 12 + kx) * 4 + 1] = li + hi;  // Pi
    PQ[(j * 12 + kx) * 4 + 2] = hi - li;  // Qr
    PQ[(j * 12 + kx) * 4 + 3] = lr - hr;  // Qi
  }
  __syncthreads();

  // Phase A: inverse ky-DFT -> Gs (t < 192: 16 hq x 12 kx)
  if (t < 192) {
    const int kx = t % 12, hq = t / 12;  // hq 0..15
    float Pr[13], Pi[13], Qr[13], Qi[13];
#pragma unroll
    for (int j = 0; j < 13; j++) {
      Pr[j] = PQ[(j * 12 + kx) * 4 + 0];
      Pi[j] = PQ[(j * 12 + kx) * 4 + 1];
      Qr[j] = PQ[(j * 12 + kx) * 4 + 2];
      Qi[j] = PQ[(j * 12 + kx) * 4 + 3];
    }
    for (int hh = 0; hh < 8; hh++) {
      int h = hh * 16 + hq;  // 0..127
      float Er = 0, Ei = 0, Or = 0, Oi = 0;
#pragma unroll
      for (int j = 0; j < 13; j++) {
        float c = tw[h * 27 + 2 * j], s = tw[h * 27 + 2 * j + 1];
        if (j & 1) {
          Or = fmaf(Pr[j], c, Or); Or = fmaf(Qr[j], s, Or);
          Oi = fmaf(Pi[j], c, Oi); Oi = fmaf(Qi[j], s, Oi);
        } else {
          Er = fmaf(Pr[j], c, Er); Er = fmaf(Qr[j], s, Er);
          Ei = fmaf(Pi[j], c, Ei); Ei = fmaf(Qi[j], s, Ei);
        }
      }
      Gs[h * 24 + 2 * kx] = Er + Or;           // G[h]
      Gs[h * 24 + 2 * kx + 1] = Ei + Oi;
      Gs[(h + 128) * 24 + 2 * kx] = Er - Or;   // G[h+128]
      Gs[(h + 128) * 24 + 2 * kx + 1] = Ei - Oi;
    }
  }

  // Phase B twiddles (independent of Gs -> before barrier)
  float cA[12], sA[12], cB[12], sB[12];
#pragma unroll
  for (int kx = 1; kx < 12; kx++) {
    float s, c;
    __sincosf(TPI * (float)((kx * (2 * l)) & 255) * (1.0f / 256.0f), &s, &c);
    cA[kx] = c; sA[kx] = s;
    __sincosf(TPI * (float)((kx * (2 * l + 1)) & 255) * (1.0f / 256.0f), &s, &c);
    cB[kx] = c; sB[kx] = s;
  }
  __syncthreads();

  // Phase B: inverse w-DFT from Gs; wave wq owns rows wq*64..wq*64+63
  float* ob0 = out + ((size_t)bo * 256 + wq * 64) * 256;
  for (int rs = 0; rs < 64; rs++) {
    int rl = wq * 64 + rs;
    float g[24];
    const float4* gr4 = reinterpret_cast<const float4*>(&Gs[rl * 24]);
#pragma unroll
    for (int qq = 0; qq < 6; qq++) {
      float4 v = gr4[qq];
      g[4 * qq] = v.x; g[4 * qq + 1] = v.y; g[4 * qq + 2] = v.z; g[4 * qq + 3] = v.w;
    }
    float E0 = g[0], O0 = 0, E1 = g[0], O1 = 0;  // DC: Re(G0) only
#pragma unroll
    for (int kx = 1; kx < 12; kx++) {
      float ta = g[2 * kx] * cA[kx] - g[2 * kx + 1] * sA[kx];
      float tb = g[2 * kx] * cB[kx] - g[2 * kx + 1] * sB[kx];
      if (kx & 1) { O0 += ta; O1 += tb; } else { E0 += ta; E1 += tb; }
    }
    float* orow = ob0 + rs * 256;
    *reinterpret_cast<float2*>(&orow[2 * l]) = make_float2(E0 + O0, E1 + O1);
    *reinterpret_cast<float2*>(&orow[128 + 2 * l]) = make_float2(E0 - O0, E1 - O1);
  }
}

extern "C" void kernel_launch(void* const* d_in, const int* in_sizes, int n_in,
                              void* d_out, int out_size, void* d_ws, size_t ws_size,
                              hipStream_t stream) {
  const float* x = (const float*)d_in[0];
  const float* w1 = (const float*)d_in[1];
  const float* w2 = (const float*)d_in[2];
  float* out = (float*)d_out;
  float* ws = (float*)d_ws;

  float* Xf = ws;               // 294,912 floats
  float* Ff = ws + 294912;      // 294,912 floats

  k12_hwdft<<<512, 256, 0, stream>>>(x, Xf);
  k3_mix<<<288, 256, 0, stream>>>(Xf, w1, w2, Ff);
  k45_inv<<<512, 256, 0, stream>>>(Ff, out);
}

// Round 17
// 74.979 us; speedup vs baseline: 1.0464x; 1.0464x over previous
//
#include <hip/hip_runtime.h>

// SpectralConv2d via pruned partial DFTs (h-DFT first), 3-kernel fused pipeline.
// x: [16,32,256,256] f32 ; w1,w2: [32,32,12,12,2] f32 ; out: [16,32,256,256] f32
//  K12: per (bi, w-half) block: radix-4 h-fold H-DFT (r15 base, best known).
//       r17: 2-pass cross-wave reduce (4 fewer barriers), dual-chain epilogue (ILP 2).
//  K3:  F[ky][kx][bo] = channel mix; sums the two Xf halves; scale folded in.
//  K45: per bo block: inverse ky-DFT -> G[bo] in LDS, then inverse w-DFT -> out.
//       r17: NONTEMPORAL out stores -> don't evict x from L3 between graph replays
//       (r14 counters: k12 re-fetched 65MB of x from HBM each iteration).

#define TPI 6.28318530717958647692f

__global__ __launch_bounds__(256, 2) void k12_hwdft(const float* __restrict__ x,
                                                    float* __restrict__ Xf) {
  __shared__ float2 step2[64];         // (cos,sin)(2pi h'/256), h'=0..63 (0.5 KB)
  __shared__ float red[4 * 13 * 128];  // cross-wave reduce, 2 passes (26.6 KB)
  __shared__ float2 Ys2[13 * 130];     // [j][w-local] {C,S}, stride 130 (13.5 KB)
  const int blk = blockIdx.x;          // 0..1023 = bi*2 + wh
  const int bi = blk >> 1, wh = blk & 1;
  const int t = threadIdx.x;
  const int q = t >> 6, l = t & 63;    // wave q -> 16 h'-groups, lane l -> 2 w's

  if (t < 64) {
    float s, c;
    sincosf(TPI * (float)t * (1.0f / 256.0f), &s, &c);
    step2[t] = make_float2(c, s);
  }
  __syncthreads();

  const float2* xp2 = reinterpret_cast<const float2*>(x + (size_t)bi * 65536 + wh * 128) + l;
  float2 aC[13], aS12[12];             // aS12[j-1] holds S_j (S_0 == 0)
#pragma unroll
  for (int j = 0; j < 13; j++) aC[j] = make_float2(0.f, 0.f);
#pragma unroll
  for (int j = 0; j < 12; j++) aS12[j] = make_float2(0.f, 0.f);

  const int h0 = q * 16;
#pragma unroll 2
  for (int hh = 0; hh < 16; hh++) {
    int h = h0 + hh;                   // h' in [0,64)
    float2 x0 = xp2[h * 128];
    float2 x1 = xp2[(h + 64) * 128];
    float2 x2 = xp2[(h + 128) * 128];
    float2 x3 = xp2[(h + 192) * 128];
    float2 p02 = make_float2(x0.x + x2.x, x0.y + x2.y);
    float2 m02 = make_float2(x0.x - x2.x, x0.y - x2.y);
    float2 p13 = make_float2(x1.x + x3.x, x1.y + x3.y);
    float2 m13 = make_float2(x1.x - x3.x, x1.y - x3.y);
    float2 A = make_float2(p02.x + p13.x, p02.y + p13.y);   // j % 4 == 0
    float2 Bv = make_float2(p02.x - p13.x, p02.y - p13.y);  // j % 4 == 2
    aC[0].x += A.x; aC[0].y += A.y;    // j=0
    float2 st = step2[h];
    float cj = st.x, sj = st.y;        // phasor at j=1
#pragma unroll
    for (int jj = 0; jj < 12; jj++) {
      const int j = jj + 1, r = j & 3;
      if (r == 0) {
        aC[j].x = fmaf(A.x, cj, aC[j].x);   aC[j].y = fmaf(A.y, cj, aC[j].y);
        aS12[jj].x = fmaf(A.x, sj, aS12[jj].x); aS12[jj].y = fmaf(A.y, sj, aS12[jj].y);
      } else if (r == 2) {
        aC[j].x = fmaf(Bv.x, cj, aC[j].x);  aC[j].y = fmaf(Bv.y, cj, aC[j].y);
        aS12[jj].x = fmaf(Bv.x, sj, aS12[jj].x); aS12[jj].y = fmaf(Bv.y, sj, aS12[jj].y);
      } else if (r == 1) {
        aC[j].x = fmaf(m02.x, cj, fmaf(-m13.x, sj, aC[j].x));
        aC[j].y = fmaf(m02.y, cj, fmaf(-m13.y, sj, aC[j].y));
        aS12[jj].x = fmaf(m02.x, sj, fmaf(m13.x, cj, aS12[jj].x));
        aS12[jj].y = fmaf(m02.y, sj, fmaf(m13.y, cj, aS12[jj].y));
      } else {
        aC[j].x = fmaf(m02.x, cj, fmaf(m13.x, sj, aC[j].x));
        aC[j].y = fmaf(m02.y, cj, fmaf(m13.y, sj, aC[j].y));
        aS12[jj].x = fmaf(m02.x, sj, fmaf(-m13.x, cj, aS12[jj].x));
        aS12[jj].y = fmaf(m02.y, sj, fmaf(-m13.y, cj, aS12[jj].y));
      }
      if (jj < 11) {
        float nc = fmaf(cj, st.x, -(sj * st.y));  // rotate by e^{i th'}
        float ns = fmaf(cj, st.y, sj * st.x);
        cj = nc; sj = ns;
      }
    }
  }

  // cross-wave reduce into Ys2: 2 passes x 13 classes (cls = 2j: C_j, 2j+1: S_j)
  for (int p = 0; p < 2; p++) {
    __syncthreads();
#pragma unroll
    for (int cc = 0; cc < 13; cc++) {
      int cls = p * 13 + cc;
      int j = cls >> 1;
      float2 v;
      if (cls & 1) v = (j == 0) ? make_float2(0.f, 0.f) : aS12[j - 1];
      else v = aC[j];
      *reinterpret_cast<float2*>(&red[(q * 13 + cc) * 128 + 2 * l]) = v;
    }
    __syncthreads();
    for (int idx = t; idx < 13 * 128; idx += 256) {
      int cc = idx >> 7, wl = idx & 127;
      int cls = p * 13 + cc;
      float s = red[(0 * 13 + cc) * 128 + wl] + red[(1 * 13 + cc) * 128 + wl] +
                red[(2 * 13 + cc) * 128 + wl] + red[(3 * 13 + cc) * 128 + wl];
      if (cls & 1) Ys2[(cls >> 1) * 130 + wl].y = s;
      else         Ys2[(cls >> 1) * 130 + wl].x = s;
    }
  }
  __syncthreads();

  // fused w-DFT: dual even/odd-w phasor chains (ILP 2, serial chain 64 steps)
  if (t < 156) {
    int j = t / 12, kx = t % 12;  // j = |ky| 0..12
    float c1, s1, c2, s2;
    {
      float s, c;
      sincosf(TPI * (float)kx * (1.0f / 256.0f), &s, &c);
      c1 = c; s1 = -s;                       // odd-chain start phasor (w=1)
      sincosf(TPI * (float)((2 * kx) & 255) * (1.0f / 256.0f), &s, &c);
      c2 = c; s2 = -s;                       // both chains step e^{-i 2 kx th}
    }
    const float2* CS = &Ys2[j * 130];
    float pr0 = 1.0f, pi0 = 0.0f;            // even chain (w=0,2,..)
    float pr1 = c1, pi1 = s1;                // odd chain  (w=1,3,..)
    float A = 0, B = 0, D = 0, E = 0;
#pragma unroll 4
    for (int w = 0; w < 128; w += 2) {
      float4 vv = *reinterpret_cast<const float4*>(&CS[w]);  // {C_w,S_w,C_w+1,S_w+1}
      A = fmaf(vv.x, pr0, A); B = fmaf(vv.x, pi0, B);
      D = fmaf(vv.y, pr0, D); E = fmaf(vv.y, pi0, E);
      A = fmaf(vv.z, pr1, A); B = fmaf(vv.z, pi1, B);
      D = fmaf(vv.w, pr1, D); E = fmaf(vv.w, pi1, E);
      float n0r = pr0 * c2 - pi0 * s2, n0i = pr0 * s2 + pi0 * c2;
      float n1r = pr1 * c2 - pi1 * s2, n1i = pr1 * s2 + pi1 * c2;
      pr0 = n0r; pi0 = n0i; pr1 = n1r; pi1 = n1i;
    }
    // global w = wh*128 + w'  ->  multiply by (-1)^(kx*wh)
    float sgn = (wh && (kx & 1)) ? -1.0f : 1.0f;
    A *= sgn; B *= sgn; D *= sgn; E *= sgn;
    float2* Xo = reinterpret_cast<float2*>(Xf) + (size_t)wh * 147456;
    size_t base = (size_t)kx * 512 + bi;
    if (j <= 11) Xo[(size_t)j * 6144 + base] = make_float2(A + E, B - D);
    if (j >= 1)  Xo[(size_t)(24 - j) * 6144 + base] = make_float2(A - E, B + D);
  }
}

__global__ __launch_bounds__(256) void k3_mix(const float* __restrict__ Xf,
                                              const float* __restrict__ w1,
                                              const float* __restrict__ w2,
                                              float* __restrict__ Ff) {
  __shared__ float Xs[1024];  // [b][i][2]
  __shared__ float Ws[2048];  // [i][o][2]
  int m = blockIdx.x;         // ky*12 + kx, 288 blocks
  int ky = m / 12, kx = m % 12;
  int t = threadIdx.x;
  const float* Xsl = Xf + (size_t)m * 1024;
  for (int e = t; e < 1024; e += 256) Xs[e] = Xsl[e] + Xsl[e + 294912];  // sum halves
  const float* Wp = (ky < 12) ? w1 : w2;
  int myr = (ky < 12) ? ky : ky - 12;
  int woff = myr * 24 + kx * 2;
  for (int e = t; e < 1024; e += 256) {  // e = i*32 + o
    float2 wv = *reinterpret_cast<const float2*>(Wp + (size_t)e * 288 + woff);
    Ws[e * 2] = wv.x; Ws[e * 2 + 1] = wv.y;
  }
  __syncthreads();
  int o = t & 31, bh = t >> 5;  // bh 0..7 ; handles b = bh and bh+8
  float ar = 0, ai = 0, br = 0, bi_ = 0;
#pragma unroll
  for (int i = 0; i < 32; i++) {
    float wr = Ws[i * 64 + o * 2], wi = Ws[i * 64 + o * 2 + 1];
    float x1r = Xs[bh * 64 + i * 2], x1i = Xs[bh * 64 + i * 2 + 1];
    float x2r = Xs[(bh + 8) * 64 + i * 2], x2i = Xs[(bh + 8) * 64 + i * 2 + 1];
    ar = fmaf(x1r, wr, ar); ar = fmaf(-x1i, wi, ar);
    ai = fmaf(x1r, wi, ai); ai = fmaf(x1i, wr, ai);
    br = fmaf(x2r, wr, br); br = fmaf(-x2i, wi, br);
    bi_ = fmaf(x2r, wi, bi_); bi_ = fmaf(x2i, wr, bi_);
  }
  float scale = (kx == 0 ? 1.0f : 2.0f) * (1.0f / 65536.0f);
  float2* Fo = reinterpret_cast<float2*>(Ff) + (size_t)m * 512;
  Fo[(size_t)bh * 32 + o] = make_float2(ar * scale, ai * scale);
  Fo[(size_t)(bh + 8) * 32 + o] = make_float2(br * scale, bi_ * scale);
}

__global__ __launch_bounds__(256) void k45_inv(const float* __restrict__ Ff,
                                               float* __restrict__ out) {
  __shared__ float tw[128 * 27];     // [h][2j+{c,s}], pad 27 (13.8 KB)
  __shared__ float PQ[13 * 12 * 4];  // [j][kx][{Pr,Pi,Qr,Qi}] (2.4 KB)
  __shared__ float Gs[256 * 24];     // G[bo] rows (24.6 KB)
  const int bo = blockIdx.x;         // 0..511
  const int t = threadIdx.x;         // 0..255
  const int l = t & 63, wq = t >> 6;

  for (int e = t; e < 128 * 13; e += 256) {
    int h = e / 13, j = e % 13;
    float s, c;
    sincosf(TPI * (float)((h * j) & 255) * (1.0f / 256.0f), &s, &c);
    tw[h * 27 + 2 * j] = c;
    tw[h * 27 + 2 * j + 1] = s;
  }
  if (t < 156) {
    int j = t / 12, kx = t % 12;
    const float2* F2 = reinterpret_cast<const float2*>(Ff);
    float lr = 0, li = 0, hr = 0, hi = 0;
    if (j < 12) { float2 v = F2[((size_t)j * 12 + kx) * 512 + bo]; lr = v.x; li = v.y; }
    if (j > 0)  { float2 v = F2[((size_t)(24 - j) * 12 + kx) * 512 + bo]; hr = v.x; hi = v.y; }
    PQ[(j * 12 + kx) * 4 + 0] = lr + hr;  // Pr
    PQ[(j * 12 + kx) * 4 + 1] = li + hi;  // Pi
    PQ[(j * 12 + kx) * 4 + 2] = hi - li;  // Qr
    PQ[(j * 12 + kx) * 4 + 3] = lr - hr;  // Qi
  }
  __syncthreads();

  // Phase A: inverse ky-DFT -> Gs (t < 192: 16 hq x 12 kx)
  if (t < 192) {
    const int kx = t % 12, hq = t / 12;  // hq 0..15
    float Pr[13], Pi[13], Qr[13], Qi[13];
#pragma unroll
    for (int j = 0; j < 13; j++) {
      Pr[j] = PQ[(j * 12 + kx) * 4 + 0];
      Pi[j] = PQ[(j * 12 + kx) * 4 + 1];
      Qr[j] = PQ[(j * 12 + kx) * 4 + 2];
      Qi[j] = PQ[(j * 12 + kx) * 4 + 3];
    }
    for (int hh = 0; hh < 8; hh++) {
      int h = hh * 16 + hq;  // 0..127
      float Er = 0, Ei = 0, Or = 0, Oi = 0;
#pragma unroll
      for (int j = 0; j < 13; j++) {
        float c = tw[h * 27 + 2 * j], s = tw[h * 27 + 2 * j + 1];
        if (j & 1) {
          Or = fmaf(Pr[j], c, Or); Or = fmaf(Qr[j], s, Or);
          Oi = fmaf(Pi[j], c, Oi); Oi = fmaf(Qi[j], s, Oi);
        } else {
          Er = fmaf(Pr[j], c, Er); Er = fmaf(Qr[j], s, Er);
          Ei = fmaf(Pi[j], c, Ei); Ei = fmaf(Qi[j], s, Ei);
        }
      }
      Gs[h * 24 + 2 * kx] = Er + Or;           // G[h]
      Gs[h * 24 + 2 * kx + 1] = Ei + Oi;
      Gs[(h + 128) * 24 + 2 * kx] = Er - Or;   // G[h+128]
      Gs[(h + 128) * 24 + 2 * kx + 1] = Ei - Oi;
    }
  }

  // Phase B twiddles (independent of Gs -> before barrier)
  float cA[12], sA[12], cB[12], sB[12];
#pragma unroll
  for (int kx = 1; kx < 12; kx++) {
    float s, c;
    __sincosf(TPI * (float)((kx * (2 * l)) & 255) * (1.0f / 256.0f), &s, &c);
    cA[kx] = c; sA[kx] = s;
    __sincosf(TPI * (float)((kx * (2 * l + 1)) & 255) * (1.0f / 256.0f), &s, &c);
    cB[kx] = c; sB[kx] = s;
  }
  __syncthreads();

  // Phase B: inverse w-DFT from Gs; NONTEMPORAL stores (don't evict x from L3)
  float* ob0 = out + ((size_t)bo * 256 + wq * 64) * 256;
  for (int rs = 0; rs < 64; rs++) {
    int rl = wq * 64 + rs;
    float g[24];
    const float4* gr4 = reinterpret_cast<const float4*>(&Gs[rl * 24]);
#pragma unroll
    for (int qq = 0; qq < 6; qq++) {
      float4 v = gr4[qq];
      g[4 * qq] = v.x; g[4 * qq + 1] = v.y; g[4 * qq + 2] = v.z; g[4 * qq + 3] = v.w;
    }
    float E0 = g[0], O0 = 0, E1 = g[0], O1 = 0;  // DC: Re(G0) only
#pragma unroll
    for (int kx = 1; kx < 12; kx++) {
      float ta = g[2 * kx] * cA[kx] - g[2 * kx + 1] * sA[kx];
      float tb = g[2 * kx] * cB[kx] - g[2 * kx + 1] * sB[kx];
      if (kx & 1) { O0 += ta; O1 += tb; } else { E0 += ta; E1 += tb; }
    }
    float* orow = ob0 + rs * 256;
    float2 v0 = make_float2(E0 + O0, E1 + O1);
    float2 v1 = make_float2(E0 - O0, E1 - O1);
    __builtin_nontemporal_store(*reinterpret_cast<double*>(&v0),
                                reinterpret_cast<double*>(&orow[2 * l]));
    __builtin_nontemporal_store(*reinterpret_cast<double*>(&v1),
                                reinterpret_cast<double*>(&orow[128 + 2 * l]));
  }
}

extern "C" void kernel_launch(void* const* d_in, const int* in_sizes, int n_in,
                              void* d_out, int out_size, void* d_ws, size_t ws_size,
                              hipStream_t stream) {
  const float* x = (const float*)d_in[0];
  const float* w1 = (const float*)d_in[1];
  const float* w2 = (const float*)d_in[2];
  float* out = (float*)d_out;
  float* ws = (float*)d_ws;

  float* Xf = ws;               // 2 x 294,912 floats (partial halves)
  float* Ff = ws + 589824;      //     294,912 floats

  k12_hwdft<<<1024, 256, 0, stream>>>(x, Xf);
  k3_mix<<<288, 256, 0, stream>>>(Xf, w1, w2, Ff);
  k45_inv<<<512, 256, 0, stream>>>(Ff, out);
}

// Round 18
// 73.171 us; speedup vs baseline: 1.0723x; 1.0247x over previous
//
#include <hip/hip_runtime.h>

// SpectralConv2d via pruned partial DFTs (h-DFT first), 3-kernel fused pipeline.
// x: [16,32,256,256] f32 ; w1,w2: [32,32,12,12,2] f32 ; out: [16,32,256,256] f32
//  K12: per (bi, w-half) block: radix-4 h-fold H-DFT (r15/r17 base).
//       r18: named-var depth-1 load pipeline + unroll 4 (longer load->use distance;
//       no register arrays -> no r8 spill trap). 2-pass reduce, dual-chain epilogue.
//  K3:  F[ky][kx][bo] = channel mix; sums the two Xf halves; scale folded in.
//  K45: per bo block: inverse ky-DFT -> G[bo] in LDS, then inverse w-DFT -> out
//       with NONTEMPORAL stores (r17: preserves x's L3 residency across replays).

#define TPI 6.28318530717958647692f

__global__ __launch_bounds__(256, 2) void k12_hwdft(const float* __restrict__ x,
                                                    float* __restrict__ Xf) {
  __shared__ float2 step2[64];         // (cos,sin)(2pi h'/256), h'=0..63 (0.5 KB)
  __shared__ float red[4 * 13 * 128];  // cross-wave reduce, 2 passes (26.6 KB)
  __shared__ float2 Ys2[13 * 130];     // [j][w-local] {C,S}, stride 130 (13.5 KB)
  const int blk = blockIdx.x;          // 0..1023 = bi*2 + wh
  const int bi = blk >> 1, wh = blk & 1;
  const int t = threadIdx.x;
  const int q = t >> 6, l = t & 63;    // wave q -> 16 h'-groups, lane l -> 2 w's

  if (t < 64) {
    float s, c;
    sincosf(TPI * (float)t * (1.0f / 256.0f), &s, &c);
    step2[t] = make_float2(c, s);
  }
  __syncthreads();

  const float2* xp2 = reinterpret_cast<const float2*>(x + (size_t)bi * 65536 + wh * 128) + l;
  float2 aC[13], aS12[12];             // aS12[j-1] holds S_j (S_0 == 0)
#pragma unroll
  for (int j = 0; j < 13; j++) aC[j] = make_float2(0.f, 0.f);
#pragma unroll
  for (int j = 0; j < 12; j++) aS12[j] = make_float2(0.f, 0.f);

  const int h0 = q * 16;
  // depth-1 software pipeline: named vars only (no arrays -> no spill surface)
  float2 c0 = xp2[h0 * 128];
  float2 c1 = xp2[(h0 + 64) * 128];
  float2 c2 = xp2[(h0 + 128) * 128];
  float2 c3 = xp2[(h0 + 192) * 128];
#pragma unroll 4
  for (int hh = 0; hh < 16; hh++) {
    int h = h0 + hh;                   // h' in [0,64)
    int hn = h0 + ((hh + 1) & 15);     // next iter (wrap: harmless reload at tail)
    float2 n0 = xp2[hn * 128];
    float2 n1 = xp2[(hn + 64) * 128];
    float2 n2 = xp2[(hn + 128) * 128];
    float2 n3 = xp2[(hn + 192) * 128];
    float2 p02 = make_float2(c0.x + c2.x, c0.y + c2.y);
    float2 m02 = make_float2(c0.x - c2.x, c0.y - c2.y);
    float2 p13 = make_float2(c1.x + c3.x, c1.y + c3.y);
    float2 m13 = make_float2(c1.x - c3.x, c1.y - c3.y);
    float2 A = make_float2(p02.x + p13.x, p02.y + p13.y);   // j % 4 == 0
    float2 Bv = make_float2(p02.x - p13.x, p02.y - p13.y);  // j % 4 == 2
    aC[0].x += A.x; aC[0].y += A.y;    // j=0
    float2 st = step2[h];
    float cj = st.x, sj = st.y;        // phasor at j=1
#pragma unroll
    for (int jj = 0; jj < 12; jj++) {
      const int j = jj + 1, r = j & 3;
      if (r == 0) {
        aC[j].x = fmaf(A.x, cj, aC[j].x);   aC[j].y = fmaf(A.y, cj, aC[j].y);
        aS12[jj].x = fmaf(A.x, sj, aS12[jj].x); aS12[jj].y = fmaf(A.y, sj, aS12[jj].y);
      } else if (r == 2) {
        aC[j].x = fmaf(Bv.x, cj, aC[j].x);  aC[j].y = fmaf(Bv.y, cj, aC[j].y);
        aS12[jj].x = fmaf(Bv.x, sj, aS12[jj].x); aS12[jj].y = fmaf(Bv.y, sj, aS12[jj].y);
      } else if (r == 1) {
        aC[j].x = fmaf(m02.x, cj, fmaf(-m13.x, sj, aC[j].x));
        aC[j].y = fmaf(m02.y, cj, fmaf(-m13.y, sj, aC[j].y));
        aS12[jj].x = fmaf(m02.x, sj, fmaf(m13.x, cj, aS12[jj].x));
        aS12[jj].y = fmaf(m02.y, sj, fmaf(m13.y, cj, aS12[jj].y));
      } else {
        aC[j].x = fmaf(m02.x, cj, fmaf(m13.x, sj, aC[j].x));
        aC[j].y = fmaf(m02.y, cj, fmaf(m13.y, sj, aC[j].y));
        aS12[jj].x = fmaf(m02.x, sj, fmaf(-m13.x, cj, aS12[jj].x));
        aS12[jj].y = fmaf(m02.y, sj, fmaf(-m13.y, cj, aS12[jj].y));
      }
      if (jj < 11) {
        float nc = fmaf(cj, st.x, -(sj * st.y));  // rotate by e^{i th'}
        float ns = fmaf(cj, st.y, sj * st.x);
        cj = nc; sj = ns;
      }
    }
    c0 = n0; c1 = n1; c2 = n2; c3 = n3;
  }

  // cross-wave reduce into Ys2: 2 passes x 13 classes (cls = 2j: C_j, 2j+1: S_j)
  for (int p = 0; p < 2; p++) {
    __syncthreads();
#pragma unroll
    for (int cc = 0; cc < 13; cc++) {
      int cls = p * 13 + cc;
      int j = cls >> 1;
      float2 v;
      if (cls & 1) v = (j == 0) ? make_float2(0.f, 0.f) : aS12[j - 1];
      else v = aC[j];
      *reinterpret_cast<float2*>(&red[(q * 13 + cc) * 128 + 2 * l]) = v;
    }
    __syncthreads();
    for (int idx = t; idx < 13 * 128; idx += 256) {
      int cc = idx >> 7, wl = idx & 127;
      int cls = p * 13 + cc;
      float s = red[(0 * 13 + cc) * 128 + wl] + red[(1 * 13 + cc) * 128 + wl] +
                red[(2 * 13 + cc) * 128 + wl] + red[(3 * 13 + cc) * 128 + wl];
      if (cls & 1) Ys2[(cls >> 1) * 130 + wl].y = s;
      else         Ys2[(cls >> 1) * 130 + wl].x = s;
    }
  }
  __syncthreads();

  // fused w-DFT: dual even/odd-w phasor chains (ILP 2, serial chain 64 steps)
  if (t < 156) {
    int j = t / 12, kx = t % 12;  // j = |ky| 0..12
    float c1p, s1p, c2p, s2p;
    {
      float s, c;
      sincosf(TPI * (float)kx * (1.0f / 256.0f), &s, &c);
      c1p = c; s1p = -s;                     // odd-chain start phasor (w=1)
      sincosf(TPI * (float)((2 * kx) & 255) * (1.0f / 256.0f), &s, &c);
      c2p = c; s2p = -s;                     // both chains step e^{-i 2 kx th}
    }
    const float2* CS = &Ys2[j * 130];
    float pr0 = 1.0f, pi0 = 0.0f;            // even chain (w=0,2,..)
    float pr1 = c1p, pi1 = s1p;              // odd chain  (w=1,3,..)
    float A = 0, B = 0, D = 0, E = 0;
#pragma unroll 4
    for (int w = 0; w < 128; w += 2) {
      float4 vv = *reinterpret_cast<const float4*>(&CS[w]);  // {C_w,S_w,C_w+1,S_w+1}
      A = fmaf(vv.x, pr0, A); B = fmaf(vv.x, pi0, B);
      D = fmaf(vv.y, pr0, D); E = fmaf(vv.y, pi0, E);
      A = fmaf(vv.z, pr1, A); B = fmaf(vv.z, pi1, B);
      D = fmaf(vv.w, pr1, D); E = fmaf(vv.w, pi1, E);
      float n0r = pr0 * c2p - pi0 * s2p, n0i = pr0 * s2p + pi0 * c2p;
      float n1r = pr1 * c2p - pi1 * s2p, n1i = pr1 * s2p + pi1 * c2p;
      pr0 = n0r; pi0 = n0i; pr1 = n1r; pi1 = n1i;
    }
    // global w = wh*128 + w'  ->  multiply by (-1)^(kx*wh)
    float sgn = (wh && (kx & 1)) ? -1.0f : 1.0f;
    A *= sgn; B *= sgn; D *= sgn; E *= sgn;
    float2* Xo = reinterpret_cast<float2*>(Xf) + (size_t)wh * 147456;
    size_t base = (size_t)kx * 512 + bi;
    if (j <= 11) Xo[(size_t)j * 6144 + base] = make_float2(A + E, B - D);
    if (j >= 1)  Xo[(size_t)(24 - j) * 6144 + base] = make_float2(A - E, B + D);
  }
}

__global__ __launch_bounds__(256) void k3_mix(const float* __restrict__ Xf,
                                              const float* __restrict__ w1,
                                              const float* __restrict__ w2,
                                              float* __restrict__ Ff) {
  __shared__ float Xs[1024];  // [b][i][2]
  __shared__ float Ws[2048];  // [i][o][2]
  int m = blockIdx.x;         // ky*12 + kx, 288 blocks
  int ky = m / 12, kx = m % 12;
  int t = threadIdx.x;
  const float* Xsl = Xf + (size_t)m * 1024;
  for (int e = t; e < 1024; e += 256) Xs[e] = Xsl[e] + Xsl[e + 294912];  // sum halves
  const float* Wp = (ky < 12) ? w1 : w2;
  int myr = (ky < 12) ? ky : ky - 12;
  int woff = myr * 24 + kx * 2;
  for (int e = t; e < 1024; e += 256) {  // e = i*32 + o
    float2 wv = *reinterpret_cast<const float2*>(Wp + (size_t)e * 288 + woff);
    Ws[e * 2] = wv.x; Ws[e * 2 + 1] = wv.y;
  }
  __syncthreads();
  int o = t & 31, bh = t >> 5;  // bh 0..7 ; handles b = bh and bh+8
  float ar = 0, ai = 0, br = 0, bi_ = 0;
#pragma unroll
  for (int i = 0; i < 32; i++) {
    float wr = Ws[i * 64 + o * 2], wi = Ws[i * 64 + o * 2 + 1];
    float x1r = Xs[bh * 64 + i * 2], x1i = Xs[bh * 64 + i * 2 + 1];
    float x2r = Xs[(bh + 8) * 64 + i * 2], x2i = Xs[(bh + 8) * 64 + i * 2 + 1];
    ar = fmaf(x1r, wr, ar); ar = fmaf(-x1i, wi, ar);
    ai = fmaf(x1r, wi, ai); ai = fmaf(x1i, wr, ai);
    br = fmaf(x2r, wr, br); br = fmaf(-x2i, wi, br);
    bi_ = fmaf(x2r, wi, bi_); bi_ = fmaf(x2i, wr, bi_);
  }
  float scale = (kx == 0 ? 1.0f : 2.0f) * (1.0f / 65536.0f);
  float2* Fo = reinterpret_cast<float2*>(Ff) + (size_t)m * 512;
  Fo[(size_t)bh * 32 + o] = make_float2(ar * scale, ai * scale);
  Fo[(size_t)(bh + 8) * 32 + o] = make_float2(br * scale, bi_ * scale);
}

__global__ __launch_bounds__(256) void k45_inv(const float* __restrict__ Ff,
                                               float* __restrict__ out) {
  __shared__ float tw[128 * 27];     // [h][2j+{c,s}], pad 27 (13.8 KB)
  __shared__ float PQ[13 * 12 * 4];  // [j][kx][{Pr,Pi,Qr,Qi}] (2.4 KB)
  __shared__ float Gs[256 * 24];     // G[bo] rows (24.6 KB)
  const int bo = blockIdx.x;         // 0..511
  const int t = threadIdx.x;         // 0..255
  const int l = t & 63, wq = t >> 6;

  for (int e = t; e < 128 * 13; e += 256) {
    int h = e / 13, j = e % 13;
    float s, c;
    sincosf(TPI * (float)((h * j) & 255) * (1.0f / 256.0f), &s, &c);
    tw[h * 27 + 2 * j] = c;
    tw[h * 27 + 2 * j + 1] = s;
  }
  if (t < 156) {
    int j = t / 12, kx = t % 12;
    const float2* F2 = reinterpret_cast<const float2*>(Ff);
    float lr = 0, li = 0, hr = 0, hi = 0;
    if (j < 12) { float2 v = F2[((size_t)j * 12 + kx) * 512 + bo]; lr = v.x; li = v.y; }
    if (j > 0)  { float2 v = F2[((size_t)(24 - j) * 12 + kx) * 512 + bo]; hr = v.x; hi = v.y; }
    PQ[(j * 12 + kx) * 4 + 0] = lr + hr;  // Pr
    PQ[(j * 12 + kx) * 4 + 1] = li + hi;  // Pi
    PQ[(j * 12 + kx) * 4 + 2] = hi - li;  // Qr
    PQ[(j * 12 + kx) * 4 + 3] = lr - hr;  // Qi
  }
  __syncthreads();

  // Phase A: inverse ky-DFT -> Gs (t < 192: 16 hq x 12 kx)
  if (t < 192) {
    const int kx = t % 12, hq = t / 12;  // hq 0..15
    float Pr[13], Pi[13], Qr[13], Qi[13];
#pragma unroll
    for (int j = 0; j < 13; j++) {
      Pr[j] = PQ[(j * 12 + kx) * 4 + 0];
      Pi[j] = PQ[(j * 12 + kx) * 4 + 1];
      Qr[j] = PQ[(j * 12 + kx) * 4 + 2];
      Qi[j] = PQ[(j * 12 + kx) * 4 + 3];
    }
    for (int hh = 0; hh < 8; hh++) {
      int h = hh * 16 + hq;  // 0..127
      float Er = 0, Ei = 0, Or = 0, Oi = 0;
#pragma unroll
      for (int j = 0; j < 13; j++) {
        float c = tw[h * 27 + 2 * j], s = tw[h * 27 + 2 * j + 1];
        if (j & 1) {
          Or = fmaf(Pr[j], c, Or); Or = fmaf(Qr[j], s, Or);
          Oi = fmaf(Pi[j], c, Oi); Oi = fmaf(Qi[j], s, Oi);
        } else {
          Er = fmaf(Pr[j], c, Er); Er = fmaf(Qr[j], s, Er);
          Ei = fmaf(Pi[j], c, Ei); Ei = fmaf(Qi[j], s, Ei);
        }
      }
      Gs[h * 24 + 2 * kx] = Er + Or;           // G[h]
      Gs[h * 24 + 2 * kx + 1] = Ei + Oi;
      Gs[(h + 128) * 24 + 2 * kx] = Er - Or;   // G[h+128]
      Gs[(h + 128) * 24 + 2 * kx + 1] = Ei - Oi;
    }
  }

  // Phase B twiddles (independent of Gs -> before barrier)
  float cA[12], sA[12], cB[12], sB[12];
#pragma unroll
  for (int kx = 1; kx < 12; kx++) {
    float s, c;
    __sincosf(TPI * (float)((kx * (2 * l)) & 255) * (1.0f / 256.0f), &s, &c);
    cA[kx] = c; sA[kx] = s;
    __sincosf(TPI * (float)((kx * (2 * l + 1)) & 255) * (1.0f / 256.0f), &s, &c);
    cB[kx] = c; sB[kx] = s;
  }
  __syncthreads();

  // Phase B: inverse w-DFT from Gs; NONTEMPORAL stores (don't evict x from L3)
  float* ob0 = out + ((size_t)bo * 256 + wq * 64) * 256;
  for (int rs = 0; rs < 64; rs++) {
    int rl = wq * 64 + rs;
    float g[24];
    const float4* gr4 = reinterpret_cast<const float4*>(&Gs[rl * 24]);
#pragma unroll
    for (int qq = 0; qq < 6; qq++) {
      float4 v = gr4[qq];
      g[4 * qq] = v.x; g[4 * qq + 1] = v.y; g[4 * qq + 2] = v.z; g[4 * qq + 3] = v.w;
    }
    float E0 = g[0], O0 = 0, E1 = g[0], O1 = 0;  // DC: Re(G0) only
#pragma unroll
    for (int kx = 1; kx < 12; kx++) {
      float ta = g[2 * kx] * cA[kx] - g[2 * kx + 1] * sA[kx];
      float tb = g[2 * kx] * cB[kx] - g[2 * kx + 1] * sB[kx];
      if (kx & 1) { O0 += ta; O1 += tb; } else { E0 += ta; E1 += tb; }
    }
    float* orow = ob0 + rs * 256;
    float2 v0 = make_float2(E0 + O0, E1 + O1);
    float2 v1 = make_float2(E0 - O0, E1 - O1);
    __builtin_nontemporal_store(*reinterpret_cast<double*>(&v0),
                                reinterpret_cast<double*>(&orow[2 * l]));
    __builtin_nontemporal_store(*reinterpret_cast<double*>(&v1),
                                reinterpret_cast<double*>(&orow[128 + 2 * l]));
  }
}

extern "C" void kernel_launch(void* const* d_in, const int* in_sizes, int n_in,
                              void* d_out, int out_size, void* d_ws, size_t ws_size,
                              hipStream_t stream) {
  const float* x = (const float*)d_in[0];
  const float* w1 = (const float*)d_in[1];
  const float* w2 = (const float*)d_in[2];
  float* out = (float*)d_out;
  float* ws = (float*)d_ws;

  float* Xf = ws;               // 2 x 294,912 floats (partial halves)
  float* Ff = ws + 589824;      //     294,912 floats

  k12_hwdft<<<1024, 256, 0, stream>>>(x, Xf);
  k3_mix<<<288, 256, 0, stream>>>(Xf, w1, w2, Ff);
  k45_inv<<<512, 256, 0, stream>>>(Ff, out);
}